// Round 1
// baseline (283.062 us; speedup 1.0000x reference)
//
#include <hip/hip_runtime.h>

typedef unsigned short u16;
typedef __bf16 bf16;
typedef __attribute__((ext_vector_type(8))) __bf16 bf16x8;  // MFMA A/B frag (4 VGPRs)
typedef __attribute__((ext_vector_type(4))) float f32x4;    // MFMA C/D frag

// generic -> addrspace casts for global_load_lds (direct global->LDS DMA)
#define AS1(p) ((const __attribute__((address_space(1))) void*)(p))
#define AS3(p) ((__attribute__((address_space(3))) void*)(p))

__device__ __forceinline__ u16 f2bf(float f) {
  // round-to-nearest-even fp32 -> bf16 (RNE keeps rounding unbiased; trunc would double error)
  unsigned u = __builtin_bit_cast(unsigned, f);
  u += 0x7fffu + ((u >> 16) & 1u);
  return (u16)(u >> 16);
}

static constexpr int  B_ = 2, N_ = 2048, C_ = 1024, H_ = 8, DH_ = 128;
static constexpr long SZ_IN = (long)B_ * N_ * C_;  // 4,194,304 elems
static constexpr long SZ_W  = (long)C_ * C_;       // 1,048,576 elems

// ---------------------------------------------------------------------------
// Cast fp32 inputs -> bf16 (8 elems/thread, 16B loads & stores)
// ---------------------------------------------------------------------------
__global__ void k_cast_in(const float* __restrict__ q, const float* __restrict__ kv,
                          u16* __restrict__ qb, u16* __restrict__ kvb)
{
  const float* src = blockIdx.y ? kv : q;
  u16* dst = blockIdx.y ? kvb : qb;
  long i = ((long)blockIdx.x * 256 + threadIdx.x) * 8;
  float4 a = *(const float4*)(src + i);
  float4 b = *(const float4*)(src + i + 4);
  uint4 v;
  v.x = f2bf(a.x) | ((unsigned)f2bf(a.y) << 16);
  v.y = f2bf(a.z) | ((unsigned)f2bf(a.w) << 16);
  v.z = f2bf(b.x) | ((unsigned)f2bf(b.y) << 16);
  v.w = f2bf(b.z) | ((unsigned)f2bf(b.w) << 16);
  *(uint4*)(dst + i) = v;
}

// ---------------------------------------------------------------------------
// Cast + transpose weights: W[k][n] fp32 -> WT[n][k] bf16 (64x64 LDS tiles, +1 pad)
// z selects which of the 4 weight matrices.
// ---------------------------------------------------------------------------
__global__ void k_cast_wt(const float* __restrict__ W0, const float* __restrict__ W1,
                          const float* __restrict__ W2, const float* __restrict__ W3,
                          u16* __restrict__ WT)
{
  __shared__ u16 t[64][65];
  const float* W = (blockIdx.z == 0) ? W0 : (blockIdx.z == 1) ? W1
                 : (blockIdx.z == 2) ? W2 : W3;
  u16* dst = WT + (long)blockIdx.z * SZ_W;
  int tid = threadIdx.x;
  int n0 = blockIdx.x * 64, k0 = blockIdx.y * 64;
#pragma unroll
  for (int r = 0; r < 4; ++r) {
    int slot = r * 256 + tid;
    int row = slot >> 4, c4 = slot & 15;  // row = k-local, c4*4 = n-local
    float4 a = *(const float4*)(W + (long)(k0 + row) * 1024 + n0 + c4 * 4);
    t[c4*4+0][row] = f2bf(a.x);
    t[c4*4+1][row] = f2bf(a.y);
    t[c4*4+2][row] = f2bf(a.z);
    t[c4*4+3][row] = f2bf(a.w);
  }
  __syncthreads();
#pragma unroll
  for (int r = 0; r < 4; ++r) {
    int slot = r * 256 + tid;
    int row = slot >> 4, c4 = slot & 15;  // row = n-local, c4*4 = k-local
    uint2 v;
    v.x = t[row][c4*4+0] | ((unsigned)t[row][c4*4+1] << 16);
    v.y = t[row][c4*4+2] | ((unsigned)t[row][c4*4+3] << 16);
    *(uint2*)(dst + (long)(n0 + row) * 1024 + k0 + c4 * 4) = v;
  }
}

// ---------------------------------------------------------------------------
// m97-style GEMM mainloop: C[128,128] += A[128,K] * BT[128,K]^T, K=1024, BK=32.
// 256 threads = 4 waves in 2x2; each wave 64x64 via 4x4 of 16x16x32 MFMA.
// Staging via global_load_lds width=16 (LDS layout must be slot-linear: no pad).
// ---------------------------------------------------------------------------
__device__ __forceinline__ void gemm_main_128x128(
    const u16* __restrict__ A, const u16* __restrict__ BT,
    u16* lA, u16* lB, int m0, int n0, int tid, f32x4 acc[4][4])
{
  int w = tid >> 6, l = tid & 63, quad = l >> 4, lm = l & 15;
  int wm = w >> 1, wn = w & 1;
  int srow = tid >> 2, schunk = tid & 3;  // 128x32 tile: 4 chunks of 8 bf16 per row
  const u16* Ag = A + (long)(m0 + srow) * 1024 + schunk * 8;
  const u16* Bg = BT + (long)(n0 + srow) * 1024 + schunk * 8;
  u16* lAw = lA + w * 512;  // wave-uniform LDS base (HW scatters lane*16B)
  u16* lBw = lB + w * 512;
  for (int kb = 0; kb < 32; ++kb) {
    const u16* Agk = Ag + kb * 32;
    const u16* Bgk = Bg + kb * 32;
    __builtin_amdgcn_global_load_lds(AS1(Agk),           AS3(lAw),        16, 0, 0);
    __builtin_amdgcn_global_load_lds(AS1(Agk + 64*1024), AS3(lAw + 2048), 16, 0, 0);
    __builtin_amdgcn_global_load_lds(AS1(Bgk),           AS3(lBw),        16, 0, 0);
    __builtin_amdgcn_global_load_lds(AS1(Bgk + 64*1024), AS3(lBw + 2048), 16, 0, 0);
    __syncthreads();
    bf16x8 af[4], bfr[4];
#pragma unroll
    for (int mi = 0; mi < 4; ++mi)
      af[mi] = *(const bf16x8*)(lA + (wm*64 + mi*16 + lm)*32 + quad*8);
#pragma unroll
    for (int ni = 0; ni < 4; ++ni)
      bfr[ni] = *(const bf16x8*)(lB + (wn*64 + ni*16 + lm)*32 + quad*8);
#pragma unroll
    for (int mi = 0; mi < 4; ++mi)
#pragma unroll
      for (int ni = 0; ni < 4; ++ni)
        acc[mi][ni] = __builtin_amdgcn_mfma_f32_16x16x32_bf16(af[mi], bfr[ni], acc[mi][ni], 0, 0, 0);
    __syncthreads();
  }
}

// ---------------------------------------------------------------------------
// QKV projection. z: 0=Q (scaled by 1/sqrt(DH), layout [b][h][n][d]),
//                    1=K ([b][h][n][d]), 2=V (transposed: [b][h][d][n]).
// ---------------------------------------------------------------------------
__global__ __launch_bounds__(256, 3)
void k_gemm_qkv(const u16* __restrict__ qb, const u16* __restrict__ kvb,
                const u16* __restrict__ wt,
                const float* __restrict__ bq, const float* __restrict__ bk,
                const float* __restrict__ bv,
                u16* __restrict__ Qb, u16* __restrict__ Kb, u16* __restrict__ VTb)
{
  __shared__ u16 lA[4096], lB[4096];
  int tid = threadIdx.x;
  int z = blockIdx.z;
  const u16* A = (z == 0) ? qb : kvb;
  const u16* BT = wt + (long)z * SZ_W;
  const float* bias = (z == 0) ? bq : (z == 1) ? bk : bv;
  int m0 = blockIdx.y * 128, n0 = blockIdx.x * 128;
  f32x4 acc[4][4] = {};
  gemm_main_128x128(A, BT, lA, lB, m0, n0, tid, acc);

  int w = tid >> 6, l = tid & 63, quad = l >> 4, lm = l & 15;
  int wm = w >> 1, wn = w & 1;
  float scale = (z == 0) ? 0.08838834764831845f : 1.0f;  // fold 1/sqrt(128) into Q
#pragma unroll
  for (int ni = 0; ni < 4; ++ni) {
    int n = n0 + wn*64 + ni*16 + lm;     // output channel 0..1023
    float bb = bias[n];
    int h = n >> 7, dd = n & 127;
#pragma unroll
    for (int mi = 0; mi < 4; ++mi) {
      int mbase = m0 + wm*64 + mi*16 + quad*4;   // C-layout: row = quad*4 + reg
      int bidx = mbase >> 11, nn = mbase & 2047;
      if (z == 2) {
        // V^T [b][h][d][n]: 4 regs = 4 consecutive n -> one 8B store
        u16 o0 = f2bf(acc[mi][ni][0] + bb), o1 = f2bf(acc[mi][ni][1] + bb);
        u16 o2 = f2bf(acc[mi][ni][2] + bb), o3 = f2bf(acc[mi][ni][3] + bb);
        uint2 v; v.x = o0 | ((unsigned)o1 << 16); v.y = o2 | ((unsigned)o3 << 16);
        *(uint2*)(VTb + ((long)(bidx*8 + h)*128 + dd)*2048 + nn) = v;
      } else {
        u16* dst = (z == 0) ? Qb : Kb;
#pragma unroll
        for (int r = 0; r < 4; ++r)
          dst[((long)(bidx*8 + h)*2048 + (nn + r))*128 + dd] = f2bf((acc[mi][ni][r] + bb) * scale);
      }
    }
  }
}

// ---------------------------------------------------------------------------
// Flash attention. Block = (q-tile 128, one (b,h)); 256 threads = 4 waves,
// each wave owns 32 q-rows. K-tile 64 keys. Q frags live in registers.
// LDS: K[64][128] 16K + VT[128][64] 16K + per-wave P[32][64] 16K = 48 KiB.
// Online softmax entirely in registers (stats replicated over 16-lane groups).
// ---------------------------------------------------------------------------
__global__ __launch_bounds__(256, 2)
void k_attn(const u16* __restrict__ Qb, const u16* __restrict__ Kb,
            const u16* __restrict__ VTb, u16* __restrict__ Sout)
{
  __shared__ u16 lK[64 * 128];
  __shared__ u16 lV[128 * 64];
  __shared__ u16 lP[4 * 32 * 64];
  int tid = threadIdx.x;
  int w = tid >> 6, l = tid & 63, quad = l >> 4, lm = l & 15;
  int bh = blockIdx.y;             // b*8+h
  int q0 = blockIdx.x * 128;
  const u16* Qg = Qb + ((long)bh * 2048 + q0) * 128;
  const u16* Kg = Kb + (long)bh * 2048 * 128;
  const u16* Vg = VTb + (long)bh * 128 * 2048;

  // Q fragments in registers: wave rows w*32 .. w*32+31 (mi in {0,1}), DH=128 (kk in 0..3)
  bf16x8 qf[2][4];
#pragma unroll
  for (int mi = 0; mi < 2; ++mi)
#pragma unroll
    for (int kk = 0; kk < 4; ++kk)
      qf[mi][kk] = *(const bf16x8*)(Qg + (long)(w*32 + mi*16 + lm)*128 + kk*32 + quad*8);

  f32x4 accO[2][8] = {};
  float mrow[2][4], lrow[2][4];
#pragma unroll
  for (int mi = 0; mi < 2; ++mi)
#pragma unroll
    for (int r = 0; r < 4; ++r) { mrow[mi][r] = -1e30f; lrow[mi][r] = 0.f; }

  int krow = tid >> 4, kchunk = tid & 15;  // K tile staging: 16 chunks/row
  int vrow = tid >> 3, vchunk = tid & 7;   // VT tile staging: 8 chunks/row
  u16* lPw = lP + w * 2048;

  for (int kt = 0; kt < 32; ++kt) {
    int k0 = kt * 64;
#pragma unroll
    for (int r = 0; r < 4; ++r) {
      __builtin_amdgcn_global_load_lds(AS1(Kg + (long)(k0 + r*16 + krow)*128 + kchunk*8),
                                       AS3(lK + r*2048 + w*512), 16, 0, 0);
      __builtin_amdgcn_global_load_lds(AS1(Vg + (long)(r*32 + vrow)*2048 + k0 + vchunk*8),
                                       AS3(lV + r*2048 + w*512), 16, 0, 0);
    }
    __syncthreads();

    // S = Q * K^T (scale pre-folded into Q). Wave: 32q x 64 keys.
    f32x4 accS[2][4] = {};
#pragma unroll
    for (int kk = 0; kk < 4; ++kk) {
      bf16x8 kf[4];
#pragma unroll
      for (int ni = 0; ni < 4; ++ni)
        kf[ni] = *(const bf16x8*)(lK + (ni*16 + lm)*128 + kk*32 + quad*8);
#pragma unroll
      for (int mi = 0; mi < 2; ++mi)
#pragma unroll
        for (int ni = 0; ni < 4; ++ni)
          accS[mi][ni] = __builtin_amdgcn_mfma_f32_16x16x32_bf16(qf[mi][kk], kf[ni], accS[mi][ni], 0, 0, 0);
    }

    // online softmax; C-layout: row = quad*4+r (stats shared by the 16 lanes of a quad)
#pragma unroll
    for (int mi = 0; mi < 2; ++mi) {
#pragma unroll
      for (int r = 0; r < 4; ++r) {
        float mx = fmaxf(fmaxf(accS[mi][0][r], accS[mi][1][r]),
                         fmaxf(accS[mi][2][r], accS[mi][3][r]));
        mx = fmaxf(mx, __shfl_xor(mx, 1));
        mx = fmaxf(mx, __shfl_xor(mx, 2));
        mx = fmaxf(mx, __shfl_xor(mx, 4));
        mx = fmaxf(mx, __shfl_xor(mx, 8));
        float mold = mrow[mi][r];
        float mnew = fmaxf(mold, mx);
        float alpha = __expf(mold - mnew);   // first iter: exp(-1e30)=0 zeroes accO
        mrow[mi][r] = mnew;
        float psum = 0.f;
        int prow = (mi*16 + quad*4 + r) * 64 + lm;
#pragma unroll
        for (int ni = 0; ni < 4; ++ni) {
          float p = __expf(accS[mi][ni][r] - mnew);
          psum += p;
          lPw[prow + ni*16] = f2bf(p);       // P round-trip: C-layout -> A-layout via LDS
        }
        psum += __shfl_xor(psum, 1);
        psum += __shfl_xor(psum, 2);
        psum += __shfl_xor(psum, 4);
        psum += __shfl_xor(psum, 8);
        lrow[mi][r] = lrow[mi][r] * alpha + psum;
#pragma unroll
        for (int ni = 0; ni < 8; ++ni) accO[mi][ni][r] *= alpha;
      }
    }

    // O += P * V  (P from own wave's LDS region only -> no extra barrier needed)
#pragma unroll
    for (int ks = 0; ks < 2; ++ks) {
      bf16x8 pf[2];
#pragma unroll
      for (int mi = 0; mi < 2; ++mi)
        pf[mi] = *(const bf16x8*)(lPw + (mi*16 + lm)*64 + ks*32 + quad*8);
#pragma unroll
      for (int ni = 0; ni < 8; ++ni) {
        bf16x8 vf = *(const bf16x8*)(lV + (ni*16 + lm)*64 + ks*32 + quad*8);
#pragma unroll
        for (int mi = 0; mi < 2; ++mi)
          accO[mi][ni] = __builtin_amdgcn_mfma_f32_16x16x32_bf16(pf[mi], vf, accO[mi][ni], 0, 0, 0);
      }
    }
    __syncthreads();  // before next stage overwrites lK/lV
  }

  // epilogue: O / l -> summed [b][n][h*128+d] (bf16)
  int b = bh >> 3, h = bh & 7;
#pragma unroll
  for (int mi = 0; mi < 2; ++mi) {
    float inv[4];
#pragma unroll
    for (int r = 0; r < 4; ++r) inv[r] = 1.f / lrow[mi][r];
#pragma unroll
    for (int ni = 0; ni < 8; ++ni) {
      int c = h*128 + ni*16 + lm;
#pragma unroll
      for (int r = 0; r < 4; ++r) {
        int n = q0 + w*32 + mi*16 + quad*4 + r;
        Sout[((long)(b*2048 + n)) * 1024 + c] = f2bf(accO[mi][ni][r] * inv[r]);
      }
    }
  }
}

// ---------------------------------------------------------------------------
// Output projection: d_out = summed @ Wo + bo (fp32 out, coalesced stores)
// ---------------------------------------------------------------------------
__global__ __launch_bounds__(256, 3)
void k_gemm_out(const u16* __restrict__ S, const u16* __restrict__ WoT,
                const float* __restrict__ bo, float* __restrict__ out)
{
  __shared__ u16 lA[4096], lB[4096];
  int tid = threadIdx.x;
  int m0 = blockIdx.y * 128, n0 = blockIdx.x * 128;
  f32x4 acc[4][4] = {};
  gemm_main_128x128(S, WoT, lA, lB, m0, n0, tid, acc);

  int w = tid >> 6, l = tid & 63, quad = l >> 4, lm = l & 15;
  int wm = w >> 1, wn = w & 1;
#pragma unroll
  for (int ni = 0; ni < 4; ++ni) {
    int n = n0 + wn*64 + ni*16 + lm;
    float bb = bo[n];
#pragma unroll
    for (int mi = 0; mi < 4; ++mi) {
      int mbase = m0 + wm*64 + mi*16 + quad*4;
#pragma unroll
      for (int r = 0; r < 4; ++r)
        out[(long)(mbase + r) * 1024 + n] = acc[mi][ni][r] + bb;
    }
  }
}

// ---------------------------------------------------------------------------
// ws layout (u16 elems), total 48 MiB:
//   ABUF  [4096,1024]  q_bf16, later REUSED for summed (free after QKV GEMM)
//   KVB   [4096,1024]  kv_bf16
//   WT    4x[1024,1024] transposed bf16 weights (Wq,Wk,Wv,Wo)
//   Qb/Kb [b][h][n][d], VTb [b][h][d][n]
// ---------------------------------------------------------------------------
extern "C" void kernel_launch(void* const* d_in, const int* in_sizes, int n_in,
                              void* d_out, int out_size, void* d_ws, size_t ws_size,
                              hipStream_t stream)
{
  const float* inq  = (const float*)d_in[0];
  const float* inkv = (const float*)d_in[1];
  const float* Wq = (const float*)d_in[2];
  const float* bq = (const float*)d_in[3];
  const float* Wk = (const float*)d_in[4];
  const float* bk = (const float*)d_in[5];
  const float* Wv = (const float*)d_in[6];
  const float* bv = (const float*)d_in[7];
  const float* Wo = (const float*)d_in[8];
  const float* bo = (const float*)d_in[9];

  u16* ws   = (u16*)d_ws;
  u16* ABUF = ws;
  u16* KVB  = ws + SZ_IN;
  u16* WT   = ws + 2 * SZ_IN;
  u16* Qb   = WT + 4 * SZ_W;
  u16* Kb   = Qb + SZ_IN;
  u16* VTb  = Kb + SZ_IN;

  k_cast_in <<<dim3(2048, 2),   256, 0, stream>>>(inq, inkv, ABUF, KVB);
  k_cast_wt <<<dim3(16, 16, 4), 256, 0, stream>>>(Wq, Wk, Wv, Wo, WT);
  k_gemm_qkv<<<dim3(8, 32, 3),  256, 0, stream>>>(ABUF, KVB, WT, bq, bk, bv, Qb, Kb, VTb);
  k_attn    <<<dim3(16, 16),    256, 0, stream>>>(Qb, Kb, VTb, ABUF);
  k_gemm_out<<<dim3(8, 32),     256, 0, stream>>>(ABUF, WT + 3 * SZ_W, bo, (float*)d_out);
}

// Round 2
// 255.124 us; speedup vs baseline: 1.1095x; 1.1095x over previous
//
#include <hip/hip_runtime.h>

typedef unsigned short u16;
typedef __bf16 bf16;
typedef __attribute__((ext_vector_type(8))) __bf16 bf16x8;  // MFMA A/B frag (4 VGPRs)
typedef __attribute__((ext_vector_type(4))) float f32x4;    // MFMA C/D frag

// generic -> addrspace casts for global_load_lds (direct global->LDS DMA)
#define AS1(p) ((const __attribute__((address_space(1))) void*)(p))
#define AS3(p) ((__attribute__((address_space(3))) void*)(p))

__device__ __forceinline__ u16 f2bf(float f) {
  unsigned u = __builtin_bit_cast(unsigned, f);
  u += 0x7fffu + ((u >> 16) & 1u);
  return (u16)(u >> 16);
}

static constexpr int  B_ = 2, N_ = 2048, C_ = 1024, H_ = 8, DH_ = 128;
static constexpr long SZ_IN = (long)B_ * N_ * C_;  // 4,194,304 elems
static constexpr long SZ_W  = (long)C_ * C_;       // 1,048,576 elems

// ---------------------------------------------------------------------------
// Cast fp32 inputs -> bf16 (8 elems/thread, 16B loads & stores)
// ---------------------------------------------------------------------------
__global__ void k_cast_in(const float* __restrict__ q, const float* __restrict__ kv,
                          u16* __restrict__ qb, u16* __restrict__ kvb)
{
  const float* src = blockIdx.y ? kv : q;
  u16* dst = blockIdx.y ? kvb : qb;
  long i = ((long)blockIdx.x * 256 + threadIdx.x) * 8;
  float4 a = *(const float4*)(src + i);
  float4 b = *(const float4*)(src + i + 4);
  uint4 v;
  v.x = f2bf(a.x) | ((unsigned)f2bf(a.y) << 16);
  v.y = f2bf(a.z) | ((unsigned)f2bf(a.w) << 16);
  v.z = f2bf(b.x) | ((unsigned)f2bf(b.y) << 16);
  v.w = f2bf(b.z) | ((unsigned)f2bf(b.w) << 16);
  *(uint4*)(dst + i) = v;
}

// ---------------------------------------------------------------------------
// Cast + transpose weights: W[k][n] fp32 -> WT[n][k] bf16
// ---------------------------------------------------------------------------
__global__ void k_cast_wt(const float* __restrict__ W0, const float* __restrict__ W1,
                          const float* __restrict__ W2, const float* __restrict__ W3,
                          u16* __restrict__ WT)
{
  __shared__ u16 t[64][65];
  const float* W = (blockIdx.z == 0) ? W0 : (blockIdx.z == 1) ? W1
                 : (blockIdx.z == 2) ? W2 : W3;
  u16* dst = WT + (long)blockIdx.z * SZ_W;
  int tid = threadIdx.x;
  int n0 = blockIdx.x * 64, k0 = blockIdx.y * 64;
#pragma unroll
  for (int r = 0; r < 4; ++r) {
    int slot = r * 256 + tid;
    int row = slot >> 4, c4 = slot & 15;
    float4 a = *(const float4*)(W + (long)(k0 + row) * 1024 + n0 + c4 * 4);
    t[c4*4+0][row] = f2bf(a.x);
    t[c4*4+1][row] = f2bf(a.y);
    t[c4*4+2][row] = f2bf(a.z);
    t[c4*4+3][row] = f2bf(a.w);
  }
  __syncthreads();
#pragma unroll
  for (int r = 0; r < 4; ++r) {
    int slot = r * 256 + tid;
    int row = slot >> 4, c4 = slot & 15;
    uint2 v;
    v.x = t[row][c4*4+0] | ((unsigned)t[row][c4*4+1] << 16);
    v.y = t[row][c4*4+2] | ((unsigned)t[row][c4*4+3] << 16);
    *(uint2*)(dst + (long)(n0 + row) * 1024 + k0 + c4 * 4) = v;
  }
}

// ---------------------------------------------------------------------------
// m97-style GEMM mainloop with XOR bank swizzle.
// LDS tile rows are 32 u16 = 64 B = 4 chunks of 16 B; row stride is 16 dwords
// so unswizzled reads are 8-way bank conflicts. Swizzle: slot (r,c) holds
// global chunk c ^ ((r>>1)&3) -> reads become 2-way (free, m136).
// ---------------------------------------------------------------------------
__device__ __forceinline__ void gemm_main_128x128(
    const u16* __restrict__ A, const u16* __restrict__ BT,
    u16* lA, u16* lB, int m0, int n0, int tid, f32x4 acc[4][4])
{
  int w = tid >> 6, l = tid & 63, quad = l >> 4, lm = l & 15;
  int wm = w >> 1, wn = w & 1;
  int srow = tid >> 2, schunk = tid & 3;
  int sxw = (srow >> 1) & 3;             // staging XOR (same for srow and srow+64)
  int sxr = (lm >> 1) & 3;               // read XOR (row = 16*k + lm)
  const u16* Ag = A + (long)(m0 + srow) * 1024 + (schunk ^ sxw) * 8;
  const u16* Bg = BT + (long)(n0 + srow) * 1024 + (schunk ^ sxw) * 8;
  u16* lAw = lA + w * 512;
  u16* lBw = lB + w * 512;
  for (int kb = 0; kb < 32; ++kb) {
    const u16* Agk = Ag + kb * 32;
    const u16* Bgk = Bg + kb * 32;
    __builtin_amdgcn_global_load_lds(AS1(Agk),           AS3(lAw),        16, 0, 0);
    __builtin_amdgcn_global_load_lds(AS1(Agk + 64*1024), AS3(lAw + 2048), 16, 0, 0);
    __builtin_amdgcn_global_load_lds(AS1(Bgk),           AS3(lBw),        16, 0, 0);
    __builtin_amdgcn_global_load_lds(AS1(Bgk + 64*1024), AS3(lBw + 2048), 16, 0, 0);
    __syncthreads();
    bf16x8 af[4], bfr[4];
#pragma unroll
    for (int mi = 0; mi < 4; ++mi)
      af[mi] = *(const bf16x8*)(lA + (wm*64 + mi*16 + lm)*32 + ((quad ^ sxr))*8);
#pragma unroll
    for (int ni = 0; ni < 4; ++ni)
      bfr[ni] = *(const bf16x8*)(lB + (wn*64 + ni*16 + lm)*32 + ((quad ^ sxr))*8);
#pragma unroll
    for (int mi = 0; mi < 4; ++mi)
#pragma unroll
      for (int ni = 0; ni < 4; ++ni)
        acc[mi][ni] = __builtin_amdgcn_mfma_f32_16x16x32_bf16(af[mi], bfr[ni], acc[mi][ni], 0, 0, 0);
    __syncthreads();
  }
}

// ---------------------------------------------------------------------------
// QKV projection. z: 0=Q (scaled, [b][h][n][d]), 1=K ([b][h][n][d]),
//                 2=V (transposed [b][h][d][n]).
// ---------------------------------------------------------------------------
__global__ __launch_bounds__(256, 3)
void k_gemm_qkv(const u16* __restrict__ qb, const u16* __restrict__ kvb,
                const u16* __restrict__ wt,
                const float* __restrict__ bq, const float* __restrict__ bk,
                const float* __restrict__ bv,
                u16* __restrict__ Qb, u16* __restrict__ Kb, u16* __restrict__ VTb)
{
  __shared__ u16 lA[4096], lB[4096];
  int tid = threadIdx.x;
  int z = blockIdx.z;
  const u16* A = (z == 0) ? qb : kvb;
  const u16* BT = wt + (long)z * SZ_W;
  const float* bias = (z == 0) ? bq : (z == 1) ? bk : bv;
  int m0 = blockIdx.y * 128, n0 = blockIdx.x * 128;
  f32x4 acc[4][4] = {};
  gemm_main_128x128(A, BT, lA, lB, m0, n0, tid, acc);

  int w = tid >> 6, l = tid & 63, quad = l >> 4, lm = l & 15;
  int wm = w >> 1, wn = w & 1;
  float scale = (z == 0) ? 0.08838834764831845f : 1.0f;
#pragma unroll
  for (int ni = 0; ni < 4; ++ni) {
    int n = n0 + wn*64 + ni*16 + lm;
    float bb = bias[n];
    int h = n >> 7, dd = n & 127;
#pragma unroll
    for (int mi = 0; mi < 4; ++mi) {
      int mbase = m0 + wm*64 + mi*16 + quad*4;
      int bidx = mbase >> 11, nn = mbase & 2047;
      if (z == 2) {
        u16 o0 = f2bf(acc[mi][ni][0] + bb), o1 = f2bf(acc[mi][ni][1] + bb);
        u16 o2 = f2bf(acc[mi][ni][2] + bb), o3 = f2bf(acc[mi][ni][3] + bb);
        uint2 v; v.x = o0 | ((unsigned)o1 << 16); v.y = o2 | ((unsigned)o3 << 16);
        *(uint2*)(VTb + ((long)(bidx*8 + h)*128 + dd)*2048 + nn) = v;
      } else {
        u16* dst = (z == 0) ? Qb : Kb;
#pragma unroll
        for (int r = 0; r < 4; ++r)
          dst[((long)(bidx*8 + h)*2048 + (nn + r))*128 + dd] = f2bf((acc[mi][ni][r] + bb) * scale);
      }
    }
  }
}

// ---------------------------------------------------------------------------
// Flash attention v2. Block = 64 q-rows of one (b,h); 4 waves, each wave owns
// 16 q-rows (full 64-key tiles). Grid (bh=16, qt=32) = 512 blocks = 2/CU;
// blockIdx.x=bh so all q-tiles of a head share one XCD L2 (linear%8 = bh%8).
// LDS 40 KiB: lK[64][128], lV[128][64], per-wave lP[16][64]; all XOR-swizzled
// (slot (r,c) holds global/logical chunk c^(r&7)) -> 2-way conflicts max.
// ---------------------------------------------------------------------------
__global__ __launch_bounds__(256, 2)
void k_attn(const u16* __restrict__ Qb, const u16* __restrict__ Kb,
            const u16* __restrict__ VTb, u16* __restrict__ Sout)
{
  __shared__ u16 lK[64 * 128];
  __shared__ u16 lV[128 * 64];
  __shared__ u16 lP[4 * 16 * 64];
  int tid = threadIdx.x;
  int w = tid >> 6, l = tid & 63, quad = l >> 4, lm = l & 15;
  int bh = blockIdx.x;
  int q0 = blockIdx.y * 64;
  const u16* Qg = Qb + ((long)bh * 2048 + q0) * 128;
  const u16* Kg = Kb + (long)bh * 2048 * 128;
  const u16* Vg = VTb + (long)bh * 128 * 2048;

  // Q fragments resident: wave rows w*16..w*16+15, DH=128 (kk 0..3)
  bf16x8 qf[4];
#pragma unroll
  for (int kk = 0; kk < 4; ++kk)
    qf[kk] = *(const bf16x8*)(Qg + (long)(w*16 + lm)*128 + kk*32 + quad*8);

  f32x4 accO[8] = {};
  float mrow[4], lrow[4];
#pragma unroll
  for (int r = 0; r < 4; ++r) { mrow[r] = -1e30f; lrow[r] = 0.f; }

  int sK_row = tid >> 4, sK_c = tid & 15;  // K staging: 16 chunks/row (128 u16)
  int sV_row = tid >> 3, sV_c = tid & 7;   // V staging: 8 chunks/row (64 u16)
  u16* lPw = lP + w * 1024;
  int sxq = lm & 7;                        // fragment-read XOR (row = 16k + lm)

  for (int kt = 0; kt < 32; ++kt) {
    int k0 = kt * 64;
#pragma unroll
    for (int r = 0; r < 4; ++r) {
      int kr = r*16 + sK_row;              // key row 0..63
      __builtin_amdgcn_global_load_lds(AS1(Kg + (long)(k0 + kr)*128 + ((sK_c ^ (kr & 7)) * 8)),
                                       AS3(lK + r*2048 + w*512), 16, 0, 0);
      int vr = r*32 + sV_row;              // d row 0..127
      __builtin_amdgcn_global_load_lds(AS1(Vg + (long)vr*2048 + k0 + ((sV_c ^ (vr & 7)) * 8)),
                                       AS3(lV + r*2048 + w*512), 16, 0, 0);
    }
    __syncthreads();

    // S = Q * K^T (scale pre-folded into Q). Wave: 16q x 64 keys.
    f32x4 accS[4] = {};
#pragma unroll
    for (int kk = 0; kk < 4; ++kk) {
#pragma unroll
      for (int ni = 0; ni < 4; ++ni) {
        bf16x8 kf = *(const bf16x8*)(lK + (ni*16 + lm)*128 + (((kk*4 + quad) ^ sxq)) * 8);
        accS[ni] = __builtin_amdgcn_mfma_f32_16x16x32_bf16(qf[kk], kf, accS[ni], 0, 0, 0);
      }
    }

    // online softmax; C-layout row = quad*4 + r
#pragma unroll
    for (int r = 0; r < 4; ++r) {
      float mx = fmaxf(fmaxf(accS[0][r], accS[1][r]), fmaxf(accS[2][r], accS[3][r]));
      mx = fmaxf(mx, __shfl_xor(mx, 1));
      mx = fmaxf(mx, __shfl_xor(mx, 2));
      mx = fmaxf(mx, __shfl_xor(mx, 4));
      mx = fmaxf(mx, __shfl_xor(mx, 8));
      float mnew = fmaxf(mrow[r], mx);
      float alpha = __expf(mrow[r] - mnew);
      mrow[r] = mnew;
      int prow = quad*4 + r;
      int psw = prow & 7;
      float psum = 0.f;
#pragma unroll
      for (int ni = 0; ni < 4; ++ni) {
        float p = __expf(accS[ni][r] - mnew);
        psum += p;
        int chunk = (lm >> 3) + ni*2;
        lPw[prow*64 + ((chunk ^ psw) * 8) + (lm & 7)] = f2bf(p);
      }
      psum += __shfl_xor(psum, 1);
      psum += __shfl_xor(psum, 2);
      psum += __shfl_xor(psum, 4);
      psum += __shfl_xor(psum, 8);
      lrow[r] = lrow[r] * alpha + psum;
#pragma unroll
      for (int ni = 0; ni < 8; ++ni) accO[ni][r] *= alpha;
    }

    // O += P * V  (own wave's lP region: no barrier needed before reads)
#pragma unroll
    for (int ks = 0; ks < 2; ++ks) {
      bf16x8 pf = *(const bf16x8*)(lPw + lm*64 + (((ks*4 + quad) ^ sxq)) * 8);
#pragma unroll
      for (int ni = 0; ni < 8; ++ni) {
        bf16x8 vf = *(const bf16x8*)(lV + (ni*16 + lm)*64 + (((ks*4 + quad) ^ sxq)) * 8);
        accO[ni] = __builtin_amdgcn_mfma_f32_16x16x32_bf16(pf, vf, accO[ni], 0, 0, 0);
      }
    }
    __syncthreads();  // before next tile overwrites lK/lV
  }

  // epilogue: O / l -> summed [b][n][h*128+d] (bf16)
  int b = bh >> 3, h = bh & 7;
#pragma unroll
  for (int r = 0; r < 4; ++r) {
    float inv = 1.f / lrow[r];
    int n = q0 + w*16 + quad*4 + r;
#pragma unroll
    for (int ni = 0; ni < 8; ++ni) {
      int c = h*128 + ni*16 + lm;
      Sout[((long)(b*2048 + n)) * 1024 + c] = f2bf(accO[ni][r] * inv);
    }
  }
}

// ---------------------------------------------------------------------------
// Output projection: d_out = summed @ Wo + bo (fp32 out)
// ---------------------------------------------------------------------------
__global__ __launch_bounds__(256, 3)
void k_gemm_out(const u16* __restrict__ S, const u16* __restrict__ WoT,
                const float* __restrict__ bo, float* __restrict__ out)
{
  __shared__ u16 lA[4096], lB[4096];
  int tid = threadIdx.x;
  int m0 = blockIdx.y * 128, n0 = blockIdx.x * 128;
  f32x4 acc[4][4] = {};
  gemm_main_128x128(S, WoT, lA, lB, m0, n0, tid, acc);

  int w = tid >> 6, l = tid & 63, quad = l >> 4, lm = l & 15;
  int wm = w >> 1, wn = w & 1;
#pragma unroll
  for (int ni = 0; ni < 4; ++ni) {
    int n = n0 + wn*64 + ni*16 + lm;
    float bb = bo[n];
#pragma unroll
    for (int mi = 0; mi < 4; ++mi) {
      int mbase = m0 + wm*64 + mi*16 + quad*4;
#pragma unroll
      for (int r = 0; r < 4; ++r)
        out[(long)(mbase + r) * 1024 + n] = acc[mi][ni][r] + bb;
    }
  }
}

// ---------------------------------------------------------------------------
// ws layout (u16 elems), 48 MiB: ABUF (q_bf16, reused for summed), KVB,
// WT 4x, Qb/Kb [b][h][n][d], VTb [b][h][d][n]
// ---------------------------------------------------------------------------
extern "C" void kernel_launch(void* const* d_in, const int* in_sizes, int n_in,
                              void* d_out, int out_size, void* d_ws, size_t ws_size,
                              hipStream_t stream)
{
  const float* inq  = (const float*)d_in[0];
  const float* inkv = (const float*)d_in[1];
  const float* Wq = (const float*)d_in[2];
  const float* bq = (const float*)d_in[3];
  const float* Wk = (const float*)d_in[4];
  const float* bk = (const float*)d_in[5];
  const float* Wv = (const float*)d_in[6];
  const float* bv = (const float*)d_in[7];
  const float* Wo = (const float*)d_in[8];
  const float* bo = (const float*)d_in[9];

  u16* ws   = (u16*)d_ws;
  u16* ABUF = ws;
  u16* KVB  = ws + SZ_IN;
  u16* WT   = ws + 2 * SZ_IN;
  u16* Qb   = WT + 4 * SZ_W;
  u16* Kb   = Qb + SZ_IN;
  u16* VTb  = Kb + SZ_IN;

  k_cast_in <<<dim3(2048, 2),   256, 0, stream>>>(inq, inkv, ABUF, KVB);
  k_cast_wt <<<dim3(16, 16, 4), 256, 0, stream>>>(Wq, Wk, Wv, Wo, WT);
  k_gemm_qkv<<<dim3(8, 32, 3),  256, 0, stream>>>(ABUF, KVB, WT, bq, bk, bv, Qb, Kb, VTb);
  k_attn    <<<dim3(16, 32),    256, 0, stream>>>(Qb, Kb, VTb, ABUF);
  k_gemm_out<<<dim3(8, 32),     256, 0, stream>>>(ABUF, WT + 3 * SZ_W, bo, (float*)d_out);
}